// Round 2
// baseline (632.375 us; speedup 1.0000x reference)
//
#include <hip/hip_runtime.h>
#include <hip/hip_bf16.h>

#define B_DIM 32
#define N_DIM 16384
#define D 128
#define LPAD 136              // padded LDS row stride (bf16 elems)
#define SUM_CHUNKS 64         // chunks per batch for the column-sum pass

typedef __attribute__((ext_vector_type(8))) short short8;   // 8 bf16 = 4 VGPRs
typedef __attribute__((ext_vector_type(4))) float floatx4;  // MFMA accumulator

__device__ __forceinline__ short f2bf(float f) {
    unsigned u = __builtin_bit_cast(unsigned, f);
    u = (u + 0x7FFFu + ((u >> 16) & 1u)) >> 16;
    return (short)u;
}

// packed fp32x8 -> bf16x8 using v_cvt_pk_bf16_f32
__device__ __forceinline__ short8 cvt8(float4 a, float4 b) {
    union { __hip_bfloat162 h; unsigned u; } p;
    short8 r;
    p.h = __float22bfloat162_rn(make_float2(a.x, a.y)); r[0] = (short)p.u; r[1] = (short)(p.u >> 16);
    p.h = __float22bfloat162_rn(make_float2(a.z, a.w)); r[2] = (short)p.u; r[3] = (short)(p.u >> 16);
    p.h = __float22bfloat162_rn(make_float2(b.x, b.y)); r[4] = (short)p.u; r[5] = (short)(p.u >> 16);
    p.h = __float22bfloat162_rn(make_float2(b.z, b.w)); r[6] = (short)p.u; r[7] = (short)(p.u >> 16);
    return r;
}

// ---------------------------------------------------------------------------
// Kernel 1: per-chunk column sums of x. grid = B*SUM_CHUNKS x 256.
// 2048 blocks (8/CU), 4 independent accumulators -> 4 loads in flight/thread.
// ---------------------------------------------------------------------------
__global__ __launch_bounds__(256, 4) void colsum_kernel(const float* __restrict__ x,
                                                        float* __restrict__ part) {
    const int CHUNK = N_DIM / SUM_CHUNKS;   // 256 rows
    int b = blockIdx.x / SUM_CHUNKS;
    int chunk = blockIdx.x % SUM_CHUNKS;
    const float4* xp = (const float4*)(x + ((size_t)b * N_DIM + (size_t)chunk * CHUNK) * D);
    int cg = threadIdx.x & 31;   // column group (4 floats)
    int rl = threadIdx.x >> 5;   // row lane 0..7
    float4 a0 = make_float4(0.f,0.f,0.f,0.f), a1 = a0, a2 = a0, a3 = a0;
    for (int i = 0; i < 32; i += 4) {
        float4 v0 = xp[(size_t)(rl + 8*(i+0)) * 32 + cg];
        float4 v1 = xp[(size_t)(rl + 8*(i+1)) * 32 + cg];
        float4 v2 = xp[(size_t)(rl + 8*(i+2)) * 32 + cg];
        float4 v3 = xp[(size_t)(rl + 8*(i+3)) * 32 + cg];
        a0.x += v0.x; a0.y += v0.y; a0.z += v0.z; a0.w += v0.w;
        a1.x += v1.x; a1.y += v1.y; a1.z += v1.z; a1.w += v1.w;
        a2.x += v2.x; a2.y += v2.y; a2.z += v2.z; a2.w += v2.w;
        a3.x += v3.x; a3.y += v3.y; a3.z += v3.z; a3.w += v3.w;
    }
    a0.x += a1.x + a2.x + a3.x; a0.y += a1.y + a2.y + a3.y;
    a0.z += a1.z + a2.z + a3.z; a0.w += a1.w + a2.w + a3.w;
    __shared__ float4 red[256];
    red[threadIdx.x] = a0;
    __syncthreads();
    if (threadIdx.x < 32) {
        float4 s = red[threadIdx.x];
        #pragma unroll
        for (int i = 1; i < 8; i++) {
            float4 v = red[threadIdx.x + 32 * i];
            s.x += v.x; s.y += v.y; s.z += v.z; s.w += v.w;
        }
        ((float4*)(part + (size_t)blockIdx.x * D))[cg] = s;
    }
}

// ---------------------------------------------------------------------------
// Kernel 2: pooled_bias[b][e] = bias[e] + sum_d xsum[b][d] * w2[d][e]
// ---------------------------------------------------------------------------
__global__ __launch_bounds__(128) void pooled_kernel(const float* __restrict__ part,
                                                     const float* __restrict__ w2,
                                                     const float* __restrict__ bias,
                                                     float* __restrict__ pooled) {
    int b = blockIdx.x;
    int e = threadIdx.x;
    __shared__ float xs[D];
    float s = 0.f;
    for (int c = 0; c < SUM_CHUNKS; c++)
        s += part[((size_t)b * SUM_CHUNKS + c) * D + e];
    xs[e] = s;
    __syncthreads();
    float acc = bias[e];
    #pragma unroll 8
    for (int d0 = 0; d0 < D; d0++) acc += xs[d0] * w2[d0 * D + e];
    pooled[b * D + e] = acc;
}

// ---------------------------------------------------------------------------
// Kernel 3: out[b,n,e] = (x @ w1)[b,n,e] + pooled_bias[b,e]
// MFMA with SWAPPED operands: D[e_local][n_local] so each lane holds 4
// contiguous e-values for one n -> float4 stores (4x fewer store instrs).
// grid = 1024 x 256 (4 waves). Block = 512 rows; wave = 128 rows.
// ---------------------------------------------------------------------------
__global__ __launch_bounds__(256, 4) void gemm_kernel(const float* __restrict__ x,
                                                      const float* __restrict__ w1,
                                                      const float* __restrict__ pooled,
                                                      float* __restrict__ out) {
    __shared__ __align__(16) short w1t[D * LPAD];   // ~34 KB -> 4 blocks/CU
    for (int idx = threadIdx.x; idx < D * D; idx += 256) {
        int d0 = idx >> 7;       // k index
        int e  = idx & 127;      // output col
        w1t[e * LPAD + d0] = f2bf(w1[idx]);   // w1t[e][k]
    }
    __syncthreads();

    const int CHUNKS = 32;                   // 512 rows per block
    int b     = blockIdx.x / CHUNKS;
    int chunk = blockIdx.x % CHUNKS;
    int wave  = threadIdx.x >> 6;
    int lane  = threadIdx.x & 63;
    int m     = lane & 15;                   // n_local (B col / D col)
    int quad  = lane >> 4;                   // k-chunk selector / D row group

    size_t rowbase = (size_t)b * N_DIM + (size_t)chunk * 512 + (size_t)wave * 128;

    // pooled_bias float4 for this lane's 4 e-values per tile (loop-invariant)
    float4 pb[8];
    #pragma unroll
    for (int et = 0; et < 8; et++)
        pb[et] = *(const float4*)&pooled[b * D + et * 16 + quad * 4];

    for (int t = 0; t < 8; t++) {
        const float* xrow = x + (rowbase + (size_t)t * 16 + m) * D + quad * 8;
        floatx4 acc[8];
        #pragma unroll
        for (int et = 0; et < 8; et++) acc[et] = (floatx4){0.f, 0.f, 0.f, 0.f};

        #pragma unroll
        for (int ks = 0; ks < 4; ks++) {
            // B fragment (x): B[k][n]: lane holds x[n=m][k = ks*32 + quad*8 + j]
            float4 x0 = *(const float4*)(xrow + ks * 32);
            float4 x1 = *(const float4*)(xrow + ks * 32 + 4);
            short8 xf = cvt8(x0, x1);
            #pragma unroll
            for (int et = 0; et < 8; et++) {
                // A fragment (w1^T): A[e_local = m][k = ks*32 + quad*8 + j]
                short8 wf = *(const short8*)&w1t[(et * 16 + m) * LPAD + ks * 32 + quad * 8];
                acc[et] = __builtin_amdgcn_mfma_f32_16x16x32_bf16(wf, xf, acc[et], 0, 0, 0);
            }
        }

        // D layout: col = lane&15 = n_local, row = quad*4 + reg = e_local
        float* orow = out + (rowbase + (size_t)t * 16 + m) * D;
        #pragma unroll
        for (int et = 0; et < 8; et++) {
            float4 o;
            o.x = acc[et][0] + pb[et].x;
            o.y = acc[et][1] + pb[et].y;
            o.z = acc[et][2] + pb[et].z;
            o.w = acc[et][3] + pb[et].w;
            *(float4*)(orow + et * 16 + quad * 4) = o;
        }
    }
}

extern "C" void kernel_launch(void* const* d_in, const int* in_sizes, int n_in,
                              void* d_out, int out_size, void* d_ws, size_t ws_size,
                              hipStream_t stream) {
    const float* x    = (const float*)d_in[0];
    const float* w1   = (const float*)d_in[1];
    const float* w2   = (const float*)d_in[2];
    const float* bias = (const float*)d_in[3];
    float* out = (float*)d_out;

    float* part   = (float*)d_ws;                              // B*SUM_CHUNKS*D
    float* pooled = part + (size_t)B_DIM * SUM_CHUNKS * D;     // B*D

    colsum_kernel<<<B_DIM * SUM_CHUNKS, 256, 0, stream>>>(x, part);
    pooled_kernel<<<B_DIM, 128, 0, stream>>>(part, w2, bias, pooled);
    gemm_kernel<<<B_DIM * 32, 256, 0, stream>>>(x, w1, pooled, out);
}